// Round 1
// baseline (560.688 us; speedup 1.0000x reference)
//
#include <hip/hip_runtime.h>
#include <hip/hip_bf16.h>

// HypergraphGNN on MI355X (gfx950).
// B=4 P=8 N=E=2000 IN=16 HID=128 NL=3 MULT=4. All f32 inputs; internal bf16 MFMA.
// Scratch requirement: ~135 MB (see layout in kernel_launch).
//
// Pipeline:
//   convH:      H f32 [4][2000][2000] -> Hb, HTb bf16 [4][2048][2048] (zero-padded)
//   transposeW: all weight matrices -> bf16 transposed (BT operand form)
//   x0:         x = nf @ W_in (K=16, fp32 math) -> xb [32][2048][128] + xTb [32][128][2048]
//   per layer:  agg = HT@x ; e = relu(agg@Wedge) (write eT only) ;
//               agg = H@eT' ; x = relu(agg@Wnode) (write x and xT)
//   MLP:        h = relu(x@W1) ; h2 = h@W2 ; out = 10*tanh((h2.Wdec)/sqrt(128))

typedef __attribute__((ext_vector_type(8))) short bf16x8;
typedef __attribute__((ext_vector_type(4))) float f32x4;

#define GLL16(gp, lp) __builtin_amdgcn_global_load_lds(                      \
    (const __attribute__((address_space(1))) void*)(gp),                     \
    (__attribute__((address_space(3))) void*)(lp), 16, 0, 0)

__device__ __forceinline__ unsigned short f2bf(float v) {
  __hip_bfloat16 h = __float2bfloat16(v);
  return __builtin_bit_cast(unsigned short, h);
}
__device__ __forceinline__ float bf2f(unsigned short u) {
  unsigned int x = ((unsigned int)u) << 16;
  return __builtin_bit_cast(float, x);
}

// ---------------------------------------------------------------------------
// H f32 -> Hb (straight) + HTb (transposed), bf16, padded 2000->2048 w/ zeros
__global__ void convH_k(const float* __restrict__ H,
                        unsigned short* __restrict__ Hb,
                        unsigned short* __restrict__ HTb) {
  int b  = blockIdx.z;
  int n0 = blockIdx.y * 32, e0 = blockIdx.x * 32;
  __shared__ float t[32][33];
  int tx = threadIdx.x & 31, ty = threadIdx.x >> 5;  // 8 rows per pass
  for (int r = ty; r < 32; r += 8) {
    int n = n0 + r, e = e0 + tx;
    float v = (n < 2000 && e < 2000) ? H[((long)b * 2000 + n) * 2000 + e] : 0.f;
    t[r][tx] = v;
    Hb[((long)b * 2048 + n) * 2048 + e] = f2bf(v);
  }
  __syncthreads();
  for (int r = ty; r < 32; r += 8) {
    HTb[((long)b * 2048 + (e0 + r)) * 2048 + (n0 + tx)] = f2bf(t[tx][r]);
  }
}

// generic f32 [R][C] -> bf16 [C][R]
__global__ void transposeW_k(const float* __restrict__ src,
                             unsigned short* __restrict__ dst, int R, int C) {
  __shared__ float t[32][33];
  int c0 = blockIdx.x * 32, r0 = blockIdx.y * 32;
  int tx = threadIdx.x & 31, ty = threadIdx.x >> 5;
  for (int rr = ty; rr < 32; rr += 8) {
    int rI = r0 + rr, cI = c0 + tx;
    t[rr][tx] = (rI < R && cI < C) ? src[(long)rI * C + cI] : 0.f;
  }
  __syncthreads();
  for (int rr = ty; rr < 32; rr += 8) {
    int cO = c0 + rr, rO = r0 + tx;
    if (cO < C && rO < R) dst[(long)cO * R + rO] = f2bf(t[tx][rr]);
  }
}

// x0 = nf @ W_in  (K=16). Writes xb [bp][2048][128] and xTb [bp][128][2048],
// zero padding rows/cols n in [2000,2048).
__global__ void x0_k(const float* __restrict__ nf, const float* __restrict__ Win,
                     unsigned short* __restrict__ xb, unsigned short* __restrict__ xTb) {
  int bp = blockIdx.y, n = blockIdx.x, d = threadIdx.x;  // d in [0,128)
  float v = 0.f;
  if (n < 2000) {
    const float* row = nf + ((long)bp * 2000 + n) * 16;
#pragma unroll
    for (int k = 0; k < 16; k++) v += row[k] * Win[k * 128 + d];
  }
  unsigned short bits = f2bf(v);
  xb[((long)bp * 2048 + n) * 128 + d]  = bits;
  xTb[((long)bp * 128 + d) * 2048 + n] = bits;
}

// ---------------------------------------------------------------------------
// NT GEMM: C[M][Nc] = A[M][K] @ BT[Nc][K]^T, bf16 in, fp32 acc, bf16 out.
// Tile 128x128, BK=32, 256 threads (4 waves, each 64x64 = 4x4 frags of 16x16x32).
// Optionally writes normal C (Cn, ldc) and/or transposed C (Ct, ldct), fused ReLU.
// All dims must be multiples of the tile (buffers are padded).
template <int RELU, int WN, int WT>
__global__ __launch_bounds__(256) void gemm_nt(
    const unsigned short* __restrict__ A, int lda, long strideA, int aDiv,
    const unsigned short* __restrict__ BT, int ldbt, long strideBT,
    unsigned short* __restrict__ Cn, int ldc, long strideCn,
    unsigned short* __restrict__ Ct, int ldct, long strideCt, int K) {
  int bz = blockIdx.z;
  A  += (long)(bz / aDiv) * strideA;
  BT += (long)bz * strideBT;
  int m0 = blockIdx.x * 128;
  int n0 = blockIdx.y * 128;

  __shared__ unsigned short As[128 * 32];
  __shared__ unsigned short Bs[128 * 32];

  int tid  = threadIdx.x;
  int lane = tid & 63;
  int w    = tid >> 6;
  int wr   = w >> 1, wc = w & 1;

  // staging: 256 thr x 16B = 64 rows x 64B per issue; 2 issues per operand
  int sr = tid >> 2;         // row in 64-row chunk
  int sc = (tid & 3) * 8;    // bf16 element offset 0/8/16/24

  const unsigned short* Ag0 = A + (long)(m0 + sr) * lda + sc;
  const unsigned short* Ag1 = A + (long)(m0 + 64 + sr) * lda + sc;
  const unsigned short* Bg0 = BT + (long)(n0 + sr) * ldbt + sc;
  const unsigned short* Bg1 = BT + (long)(n0 + 64 + sr) * ldbt + sc;
  unsigned short* Al0 = &As[sr * 32 + sc];
  unsigned short* Al1 = &As[(64 + sr) * 32 + sc];
  unsigned short* Bl0 = &Bs[sr * 32 + sc];
  unsigned short* Bl1 = &Bs[(64 + sr) * 32 + sc];

  f32x4 acc[4][4] = {};

  int fr = lane & 15;          // A row / B col / C col within fragment
  int fg = (lane >> 4) * 8;    // k offset within fragment

  for (int k0 = 0; k0 < K; k0 += 32) {
    GLL16(Ag0 + k0, Al0);
    GLL16(Ag1 + k0, Al1);
    GLL16(Bg0 + k0, Bl0);
    GLL16(Bg1 + k0, Bl1);
    __syncthreads();  // drains vmcnt -> LDS tile ready

    bf16x8 af[4], bfv[4];
#pragma unroll
    for (int m = 0; m < 4; m++)
      af[m] = *(const bf16x8*)&As[(wr * 64 + m * 16 + fr) * 32 + fg];
#pragma unroll
    for (int n = 0; n < 4; n++)
      bfv[n] = *(const bf16x8*)&Bs[(wc * 64 + n * 16 + fr) * 32 + fg];
#pragma unroll
    for (int m = 0; m < 4; m++)
#pragma unroll
      for (int n = 0; n < 4; n++)
        acc[m][n] = __builtin_amdgcn_mfma_f32_16x16x32_bf16(af[m], bfv[n], acc[m][n], 0, 0, 0);
    __syncthreads();  // LDS consumed; safe to overwrite next iter
  }

  // epilogue: C/D frag mapping col=lane&15, row=(lane>>4)*4+r  [verified m89/m91]
#pragma unroll
  for (int m = 0; m < 4; m++) {
#pragma unroll
    for (int n = 0; n < 4; n++) {
      int rowb = m0 + wr * 64 + m * 16 + (lane >> 4) * 4;
      int ccol = n0 + wc * 64 + n * 16 + fr;
      float v0 = acc[m][n][0], v1 = acc[m][n][1], v2 = acc[m][n][2], v3 = acc[m][n][3];
      if (RELU) {
        v0 = fmaxf(v0, 0.f); v1 = fmaxf(v1, 0.f);
        v2 = fmaxf(v2, 0.f); v3 = fmaxf(v3, 0.f);
      }
      if (WN) {
        unsigned short* p = Cn + bz * strideCn + (long)rowb * ldc + ccol;
        p[0]       = f2bf(v0);
        p[ldc]     = f2bf(v1);
        p[2 * ldc] = f2bf(v2);
        p[3 * ldc] = f2bf(v3);
      }
      if (WT) {
        ushort4 pk;
        pk.x = f2bf(v0); pk.y = f2bf(v1); pk.z = f2bf(v2); pk.w = f2bf(v3);
        *(ushort4*)(Ct + bz * strideCt + (long)ccol * ldct + rowb) = pk;
      }
    }
  }
}

// ---------------------------------------------------------------------------
// out[row] = 10*tanh( dot(h2[row], Wdec) / sqrt(128) ); h2 padded-layout bf16.
__global__ void dec_k(const unsigned short* __restrict__ h2,
                      const float* __restrict__ Wdec, float* __restrict__ out) {
  int row  = blockIdx.x * 4 + (threadIdx.x >> 6);
  int lane = threadIdx.x & 63;
  int bp = row / 2000, n = row - bp * 2000;
  const unsigned short* src = h2 + ((long)bp * 2048 + n) * 128;
  float s = bf2f(src[lane]) * Wdec[lane] + bf2f(src[lane + 64]) * Wdec[lane + 64];
#pragma unroll
  for (int off = 32; off > 0; off >>= 1) s += __shfl_xor(s, off, 64);
  if (lane == 0) out[row] = 10.f * tanhf(s * 0.08838834764831843f);
}

// ---------------------------------------------------------------------------
extern "C" void kernel_launch(void* const* d_in, const int* in_sizes, int n_in,
                              void* d_out, int out_size, void* d_ws, size_t ws_size,
                              hipStream_t stream) {
  const float* nf    = (const float*)d_in[0];
  const float* H     = (const float*)d_in[1];
  const float* Win   = (const float*)d_in[2];
  const float* edgeW = (const float*)d_in[3];
  const float* nodeW = (const float*)d_in[4];
  const float* W1    = (const float*)d_in[5];
  const float* W2    = (const float*)d_in[6];
  const float* Wdec  = (const float*)d_in[7];
  float* out = (float*)d_out;

  // ---- workspace layout (bytes) ----
  // [0, 33.55M)        Hb   [4][2048][2048] bf16      } reused as hb [65536][512]
  // [33.55M, 67.11M)   HTb  [4][2048][2048] bf16      }   after last H use
  // [67.11M, 83.89M)   xb   [32][2048][128] bf16
  // [83.89M,100.66M)   xTb  [32][128][2048] bf16
  // [100.66M,117.44M)  agg  [32][2048][128] bf16  (eagg/xagg/h2, disjoint lifetimes)
  // [117.44M,134.22M)  eTb  [32][128][2048] bf16
  // [134.22M,~134.7M)  bf16 transposed weights
  char* ws = (char*)d_ws;
  unsigned short* Hb  = (unsigned short*)(ws + 0);
  unsigned short* HTb = (unsigned short*)(ws + 33554432);
  unsigned short* hb  = (unsigned short*)(ws + 0);  // aliases Hb+HTb (dead by then)
  size_t off = 67108864;
  unsigned short* xb  = (unsigned short*)(ws + off); off += 16777216;
  unsigned short* xTb = (unsigned short*)(ws + off); off += 16777216;
  unsigned short* agg = (unsigned short*)(ws + off); off += 16777216;
  unsigned short* eTb = (unsigned short*)(ws + off); off += 16777216;
  unsigned short* edgeWT = (unsigned short*)(ws + off); off += 3 * 16384 * 2;
  unsigned short* nodeWT = (unsigned short*)(ws + off); off += 3 * 16384 * 2;
  unsigned short* W1T = (unsigned short*)(ws + off); off += 65536 * 2;
  unsigned short* W2T = (unsigned short*)(ws + off); off += 65536 * 2;
  (void)ws_size; (void)in_sizes; (void)n_in; (void)out_size;

  // ---- input prep ----
  convH_k<<<dim3(64, 64, 4), 256, 0, stream>>>(H, Hb, HTb);
  for (int l = 0; l < 3; l++) {
    transposeW_k<<<dim3(4, 4), 256, 0, stream>>>(edgeW + l * 16384, edgeWT + l * 16384, 128, 128);
    transposeW_k<<<dim3(4, 4), 256, 0, stream>>>(nodeW + l * 16384, nodeWT + l * 16384, 128, 128);
  }
  transposeW_k<<<dim3(16, 4), 256, 0, stream>>>(W1, W1T, 128, 512);
  transposeW_k<<<dim3(4, 16), 256, 0, stream>>>(W2, W2T, 512, 128);
  x0_k<<<dim3(2048, 32), 128, 0, stream>>>(nf, Win, xb, xTb);

  // ---- 3 hypergraph layers ----
  for (int l = 0; l < 3; l++) {
    // eagg = H^T @ x : A=HTb (per b), BT=xTb (per bp) -> agg [bp][2048][128]
    gemm_nt<0, 1, 0><<<dim3(16, 1, 32), 256, 0, stream>>>(
        HTb, 2048, 2048L * 2048, 8, xTb, 2048, 128L * 2048,
        agg, 128, 2048L * 128, nullptr, 0, 0, 2048);
    // e = relu(eagg @ edgeW[l]) -> eTb (transposed only)
    gemm_nt<1, 0, 1><<<dim3(16, 1, 32), 256, 0, stream>>>(
        agg, 128, 2048L * 128, 1, edgeWT + l * 16384, 128, 0,
        nullptr, 0, 0, eTb, 2048, 128L * 2048, 128);
    // xagg = H @ e : A=Hb (per b), BT=eTb -> agg
    gemm_nt<0, 1, 0><<<dim3(16, 1, 32), 256, 0, stream>>>(
        Hb, 2048, 2048L * 2048, 8, eTb, 2048, 128L * 2048,
        agg, 128, 2048L * 128, nullptr, 0, 0, 2048);
    // x = relu(xagg @ nodeW[l]) -> xb (normal) + xTb (transposed)
    gemm_nt<1, 1, 1><<<dim3(16, 1, 32), 256, 0, stream>>>(
        agg, 128, 2048L * 128, 1, nodeWT + l * 16384, 128, 0,
        xb, 128, 2048L * 128, xTb, 2048, 128L * 2048, 128);
  }

  // ---- MLP ----
  // h = relu(x @ W1) : flat M=65536, Nc=512
  gemm_nt<1, 1, 0><<<dim3(512, 4, 1), 256, 0, stream>>>(
      xb, 128, 0, 1, W1T, 128, 0,
      hb, 512, 0, nullptr, 0, 0, 128);
  // h2 = h @ W2 : M=65536, Nc=128 -> agg
  gemm_nt<0, 1, 0><<<dim3(512, 1, 1), 256, 0, stream>>>(
      hb, 512, 0, 1, W2T, 512, 0,
      agg, 128, 0, nullptr, 0, 0, 512);
  // decode
  dec_k<<<dim3(16000), 256, 0, stream>>>(agg, Wdec, out);
}

// Round 2
// 484.221 us; speedup vs baseline: 1.1579x; 1.1579x over previous
//
#include <hip/hip_runtime.h>
#include <hip/hip_bf16.h>

// HypergraphGNN on MI355X (gfx950).
// B=4 P=8 N=E=2000 IN=16 HID=128 NL=3 MULT=4. All f32 inputs; internal bf16 MFMA.
//
// Round-2 structure:
//   convH: H -> Hb, HTb bf16 [4][2048][2048]
//   x0:    x = nf @ W_in -> xb + xTb
//   per layer (2 fused dispatches):
//     L1: agg = H^T@x (K=2048, swizzled LDS) ; e = relu(agg@We) fused ; write eT
//     L2: agg = H@e ; x = relu(agg@Wn) fused ; write xT (+x on last layer)
//   MLP (algebraic fusion): wf = W2@Wdec ; out = 10*tanh((relu(x@W1)@wf)/sqrt(128))
//
// LDS swizzle discipline (rule #21): LDS dest of global_load_lds is linear;
// the *global source* chunk is pre-swizzled; reads apply the same involution.
//   32-col (64B) rows:  chunk' = chunk ^ ((row>>1)&3)   -> uniform 2-way (free)
//   128-col (256B) rows: chunk' = chunk ^ (row&7)

typedef __attribute__((ext_vector_type(8))) short bf16x8;
typedef __attribute__((ext_vector_type(4))) float f32x4;

#define GLL16(gp, lp) __builtin_amdgcn_global_load_lds(                      \
    (const __attribute__((address_space(1))) void*)(gp),                     \
    (__attribute__((address_space(3))) void*)(lp), 16, 0, 0)

__device__ __forceinline__ unsigned short f2bf(float v) {
  __hip_bfloat16 h = __float2bfloat16(v);
  return __builtin_bit_cast(unsigned short, h);
}
__device__ __forceinline__ float bf2f(unsigned short u) {
  unsigned int x = ((unsigned int)u) << 16;
  return __builtin_bit_cast(float, x);
}

// ---------------------------------------------------------------------------
// H f32 -> Hb (straight) + HTb (transposed), bf16, padded 2000->2048 w/ zeros
__global__ void convH_k(const float* __restrict__ H,
                        unsigned short* __restrict__ Hb,
                        unsigned short* __restrict__ HTb) {
  int b  = blockIdx.z;
  int n0 = blockIdx.y * 32, e0 = blockIdx.x * 32;
  __shared__ float t[32][33];
  int tx = threadIdx.x & 31, ty = threadIdx.x >> 5;
  for (int r = ty; r < 32; r += 8) {
    int n = n0 + r, e = e0 + tx;
    float v = (n < 2000 && e < 2000) ? H[((long)b * 2000 + n) * 2000 + e] : 0.f;
    t[r][tx] = v;
    Hb[((long)b * 2048 + n) * 2048 + e] = f2bf(v);
  }
  __syncthreads();
  for (int r = ty; r < 32; r += 8) {
    HTb[((long)b * 2048 + (e0 + r)) * 2048 + (n0 + tx)] = f2bf(t[tx][r]);
  }
}

// generic f32 [R][C] -> bf16 [C][R]
__global__ void transposeW_k(const float* __restrict__ src,
                             unsigned short* __restrict__ dst, int R, int C) {
  __shared__ float t[32][33];
  int c0 = blockIdx.x * 32, r0 = blockIdx.y * 32;
  int tx = threadIdx.x & 31, ty = threadIdx.x >> 5;
  for (int rr = ty; rr < 32; rr += 8) {
    int rI = r0 + rr, cI = c0 + tx;
    t[rr][tx] = (rI < R && cI < C) ? src[(long)rI * C + cI] : 0.f;
  }
  __syncthreads();
  for (int rr = ty; rr < 32; rr += 8) {
    int cO = c0 + rr, rO = r0 + tx;
    if (cO < C && rO < R) dst[(long)cO * R + rO] = f2bf(t[tx][rr]);
  }
}

// x0 = nf @ W_in  (K=16). Writes xb [bp][2048][128] and xTb [bp][128][2048].
__global__ void x0_k(const float* __restrict__ nf, const float* __restrict__ Win,
                     unsigned short* __restrict__ xb, unsigned short* __restrict__ xTb) {
  int bp = blockIdx.y, n = blockIdx.x, d = threadIdx.x;
  float v = 0.f;
  if (n < 2000) {
    const float* row = nf + ((long)bp * 2000 + n) * 16;
#pragma unroll
    for (int k = 0; k < 16; k++) v += row[k] * Win[k * 128 + d];
  }
  unsigned short bits = f2bf(v);
  xb[((long)bp * 2048 + n) * 128 + d]  = bits;
  xTb[((long)bp * 128 + d) * 2048 + n] = bits;
}

// wf = W2 @ Wdec  (512x128 @ 128 -> 512)
__global__ void wfuse_k(const float* __restrict__ W2, const float* __restrict__ Wdec,
                        float* __restrict__ wf) {
  int i = blockIdx.x * 256 + threadIdx.x;
  if (i < 512) {
    float s = 0.f;
#pragma unroll 8
    for (int j = 0; j < 128; j++) s += W2[i * 128 + j] * Wdec[j];
    wf[i] = s;
  }
}

// ---------------------------------------------------------------------------
// Fused heavy GEMM: acc = A[M=2048][K] @ BT[128][K]^T, then
// out = relu(acc @ W) with W given in BT-form Wt[d][k]=W[k][d] (128x128).
// Writes Cn (normal) if WN, Ct (transposed) if WT. Tile 128x128, BK=32,
// 4 waves (each 64x64). All LDS accesses XOR-swizzled (conflict-free).
template <int WN, int WT>
__global__ __launch_bounds__(256) void gemm_fused(
    const unsigned short* __restrict__ A, int lda, long strideA, int aDiv,
    const unsigned short* __restrict__ BT, int ldbt, long strideBT,
    const unsigned short* __restrict__ Wt,
    unsigned short* __restrict__ Cn, int ldc, long strideCn,
    unsigned short* __restrict__ Ct, int ldct, long strideCt, int K) {
  int bz = blockIdx.z;
  A  += (long)(bz / aDiv) * strideA;
  BT += (long)bz * strideBT;
  int m0 = blockIdx.x * 128;

  __shared__ unsigned short As[128 * 32];   // 8 KB
  __shared__ unsigned short Bs[128 * 32];   // 8 KB
  __shared__ unsigned short Ws[128 * 128];  // 32 KB (weight, BT-form, swizzled)
  __shared__ unsigned short Gs[128 * 128];  // 32 KB (agg tile, row-major, swizzled)

  int tid  = threadIdx.x;
  int lane = tid & 63;
  int w    = tid >> 6;
  int wr   = w >> 1, wc = w & 1;
  int fr   = lane & 15;   // frag row (A) / col (B/C)
  int fg   = lane >> 4;   // k-chunk 0..3 (inputs) / row-subgroup (C/D)

  // stage Wt -> Ws once (swizzled source chunks; linear LDS dest)
#pragma unroll
  for (int i = 0; i < 8; i++) {
    int s = i * 256 + tid;
    int r = s >> 4, c = (s & 15) ^ (r & 7);
    GLL16(Wt + r * 128 + c * 8, (unsigned short*)Ws + s * 8);
  }

  // main-loop staging: LDS slot = tid*16B (linear); global chunk swizzled
  int sr  = tid >> 2;
  int scs = ((tid & 3) ^ ((sr >> 1) & 3)) * 8;
  const unsigned short* Ag0 = A + (long)(m0 + sr) * lda + scs;
  const unsigned short* Ag1 = A + (long)(m0 + 64 + sr) * lda + scs;
  const unsigned short* Bg0 = BT + (long)sr * ldbt + scs;
  const unsigned short* Bg1 = BT + (long)(64 + sr) * ldbt + scs;
  unsigned short* Al0 = As + tid * 8;
  unsigned short* Al1 = As + 2048 + tid * 8;
  unsigned short* Bl0 = Bs + tid * 8;
  unsigned short* Bl1 = Bs + 2048 + tid * 8;

  f32x4 acc[4][4] = {};
  int cIdx = ((fg ^ ((fr >> 1) & 3)) * 8);  // swizzled chunk elem-offset, 32-col tiles

  for (int k0 = 0; k0 < K; k0 += 32) {
    GLL16(Ag0 + k0, Al0);
    GLL16(Ag1 + k0, Al1);
    GLL16(Bg0 + k0, Bl0);
    GLL16(Bg1 + k0, Bl1);
    __syncthreads();
    bf16x8 af[4], bfv[4];
#pragma unroll
    for (int m = 0; m < 4; m++)
      af[m] = *(const bf16x8*)&As[(wr * 64 + m * 16 + fr) * 32 + cIdx];
#pragma unroll
    for (int n = 0; n < 4; n++)
      bfv[n] = *(const bf16x8*)&Bs[(wc * 64 + n * 16 + fr) * 32 + cIdx];
#pragma unroll
    for (int m = 0; m < 4; m++)
#pragma unroll
      for (int n = 0; n < 4; n++)
        acc[m][n] = __builtin_amdgcn_mfma_f32_16x16x32_bf16(af[m], bfv[n], acc[m][n], 0, 0, 0);
    __syncthreads();
  }

  // acc tile -> Gs bf16 row-major (swizzled). C/D map: col=lane&15, row=fg*4+r.
#pragma unroll
  for (int m = 0; m < 4; m++) {
#pragma unroll
    for (int n = 0; n < 4; n++) {
      int rowb = wr * 64 + m * 16 + fg * 4;
      int col  = wc * 64 + n * 16 + fr;
      int ch = col >> 3, ci = col & 7;
#pragma unroll
      for (int r = 0; r < 4; r++) {
        int row = rowb + r;
        Gs[row * 128 + ((ch ^ (row & 7)) * 8) + ci] = f2bf(acc[m][n][r]);
      }
    }
  }
  __syncthreads();

  // stage 2: out = relu(G @ W). A-op = Gs (row-major), B-op = Ws (BT-form).
  f32x4 acc2[4][4] = {};
#pragma unroll
  for (int kk = 0; kk < 4; kk++) {
    bf16x8 a2[4], b2[4];
#pragma unroll
    for (int m = 0; m < 4; m++) {
      int row = wr * 64 + m * 16 + fr;
      int c = kk * 4 + fg;
      a2[m] = *(const bf16x8*)&Gs[row * 128 + ((c ^ (row & 7)) * 8)];
    }
#pragma unroll
    for (int n = 0; n < 4; n++) {
      int row = wc * 64 + n * 16 + fr;
      int c = kk * 4 + fg;
      b2[n] = *(const bf16x8*)&Ws[row * 128 + ((c ^ (row & 7)) * 8)];
    }
#pragma unroll
    for (int m = 0; m < 4; m++)
#pragma unroll
      for (int n = 0; n < 4; n++)
        acc2[m][n] = __builtin_amdgcn_mfma_f32_16x16x32_bf16(a2[m], b2[n], acc2[m][n], 0, 0, 0);
  }

  // epilogue: relu + write
#pragma unroll
  for (int m = 0; m < 4; m++) {
#pragma unroll
    for (int n = 0; n < 4; n++) {
      int rowb = m0 + wr * 64 + m * 16 + fg * 4;
      int col  = wc * 64 + n * 16 + fr;
      float v0 = fmaxf(acc2[m][n][0], 0.f), v1 = fmaxf(acc2[m][n][1], 0.f);
      float v2 = fmaxf(acc2[m][n][2], 0.f), v3 = fmaxf(acc2[m][n][3], 0.f);
      if (WN) {
        unsigned short* p = Cn + bz * strideCn + (long)rowb * ldc + col;
        p[0]       = f2bf(v0);
        p[ldc]     = f2bf(v1);
        p[2 * ldc] = f2bf(v2);
        p[3 * ldc] = f2bf(v3);
      }
      if (WT) {
        ushort4 pk;
        pk.x = f2bf(v0); pk.y = f2bf(v1); pk.z = f2bf(v2); pk.w = f2bf(v3);
        *(ushort4*)(Ct + bz * strideCt + (long)col * ldct + rowb) = pk;
      }
    }
  }
}

// ---------------------------------------------------------------------------
// Fused MLP: out[row] = 10*tanh( (sum_i relu(x@W1)[row][i]*wf[i]) / sqrt(128) )
// Block: 128 rows; N-loop over 4 chunks of 128 cols of g=relu(x@W1); K=128.
__global__ __launch_bounds__(256) void mlp_k(
    const unsigned short* __restrict__ X,    // [65536][128] bf16 (padded rows)
    const unsigned short* __restrict__ W1T,  // [512][128] bf16
    const float* __restrict__ wf,            // [512]
    float* __restrict__ out) {
  __shared__ unsigned short Xs[128 * 128];   // 32 KB
  __shared__ unsigned short Bs[128 * 128];   // 32 KB
  __shared__ float rowacc[128];

  int tid  = threadIdx.x;
  int lane = tid & 63;
  int w    = tid >> 6, wr = w >> 1, wc = w & 1;
  int fr   = lane & 15, fg = lane >> 4;
  long m0  = (long)blockIdx.x * 128;

  // stage X tile (swizzled)
#pragma unroll
  for (int i = 0; i < 8; i++) {
    int s = i * 256 + tid;
    int r = s >> 4, c = (s & 15) ^ (r & 7);
    GLL16(X + (m0 + r) * 128 + c * 8, (unsigned short*)Xs + s * 8);
  }
  if (tid < 128) rowacc[tid] = 0.f;

  float rs[4][4] = {};  // [m][reg] row-partials

  for (int nb = 0; nb < 4; nb++) {
    // stage W1T rows nb*128..+127 (swizzled)
#pragma unroll
    for (int i = 0; i < 8; i++) {
      int s = i * 256 + tid;
      int r = s >> 4, c = (s & 15) ^ (r & 7);
      GLL16(W1T + (long)(nb * 128 + r) * 128 + c * 8, (unsigned short*)Bs + s * 8);
    }
    __syncthreads();

    f32x4 acc[4][4] = {};
#pragma unroll
    for (int kk = 0; kk < 4; kk++) {
      bf16x8 a2[4], b2[4];
#pragma unroll
      for (int m = 0; m < 4; m++) {
        int row = wr * 64 + m * 16 + fr;
        int c = kk * 4 + fg;
        a2[m] = *(const bf16x8*)&Xs[row * 128 + ((c ^ (row & 7)) * 8)];
      }
#pragma unroll
      for (int n = 0; n < 4; n++) {
        int row = wc * 64 + n * 16 + fr;
        int c = kk * 4 + fg;
        b2[n] = *(const bf16x8*)&Bs[row * 128 + ((c ^ (row & 7)) * 8)];
      }
#pragma unroll
      for (int m = 0; m < 4; m++)
#pragma unroll
        for (int n = 0; n < 4; n++)
          acc[m][n] = __builtin_amdgcn_mfma_f32_16x16x32_bf16(a2[m], b2[n], acc[m][n], 0, 0, 0);
    }

    // accumulate relu(g) . wf into row partials
#pragma unroll
    for (int n = 0; n < 4; n++) {
      float wv = wf[nb * 128 + wc * 64 + n * 16 + fr];
#pragma unroll
      for (int m = 0; m < 4; m++)
#pragma unroll
        for (int r = 0; r < 4; r++)
          rs[m][r] += fmaxf(acc[m][n][r], 0.f) * wv;
    }
    __syncthreads();  // before restaging Bs
  }

  // reduce over the 16-lane col dimension, then across the 2 wc waves via LDS
#pragma unroll
  for (int m = 0; m < 4; m++)
#pragma unroll
    for (int r = 0; r < 4; r++) {
      float v = rs[m][r];
      v += __shfl_xor(v, 1, 64);
      v += __shfl_xor(v, 2, 64);
      v += __shfl_xor(v, 4, 64);
      v += __shfl_xor(v, 8, 64);
      if (fr == 0) atomicAdd(&rowacc[wr * 64 + m * 16 + fg * 4 + r], v);
    }
  __syncthreads();

  if (tid < 128) {
    long row = m0 + tid;
    int bp = (int)(row >> 11), n = (int)(row & 2047);
    if (n < 2000)
      out[(long)bp * 2000 + n] = 10.f * tanhf(rowacc[tid] * 0.08838834764831843f);
  }
}

// ---------------------------------------------------------------------------
extern "C" void kernel_launch(void* const* d_in, const int* in_sizes, int n_in,
                              void* d_out, int out_size, void* d_ws, size_t ws_size,
                              hipStream_t stream) {
  const float* nf    = (const float*)d_in[0];
  const float* H     = (const float*)d_in[1];
  const float* Win   = (const float*)d_in[2];
  const float* edgeW = (const float*)d_in[3];
  const float* nodeW = (const float*)d_in[4];
  const float* W1    = (const float*)d_in[5];
  const float* W2    = (const float*)d_in[6];
  const float* Wdec  = (const float*)d_in[7];
  float* out = (float*)d_out;

  // ---- workspace layout (bytes) ----
  char* ws = (char*)d_ws;
  unsigned short* Hb   = (unsigned short*)(ws + 0);          // 33.55 MB
  unsigned short* HTb  = (unsigned short*)(ws + 33554432);   // 33.55 MB
  unsigned short* xb   = (unsigned short*)(ws + 67108864);   // 16.78 MB
  unsigned short* xTb  = (unsigned short*)(ws + 83886080);   // 16.78 MB
  unsigned short* eTb  = (unsigned short*)(ws + 100663296);  // 16.78 MB
  unsigned short* edgeWT = (unsigned short*)(ws + 117440512);
  unsigned short* nodeWT = (unsigned short*)(ws + 117538816);
  unsigned short* W1T    = (unsigned short*)(ws + 117637120);
  float*          wf     = (float*)(ws + 117768192);
  (void)ws_size; (void)in_sizes; (void)n_in; (void)out_size;

  // ---- input prep ----
  convH_k<<<dim3(64, 64, 4), 256, 0, stream>>>(H, Hb, HTb);
  for (int l = 0; l < 3; l++) {
    transposeW_k<<<dim3(4, 4), 256, 0, stream>>>(edgeW + l * 16384, edgeWT + l * 16384, 128, 128);
    transposeW_k<<<dim3(4, 4), 256, 0, stream>>>(nodeW + l * 16384, nodeWT + l * 16384, 128, 128);
  }
  transposeW_k<<<dim3(16, 4), 256, 0, stream>>>(W1, W1T, 128, 512);
  wfuse_k<<<2, 256, 0, stream>>>(W2, Wdec, wf);
  x0_k<<<dim3(2048, 32), 128, 0, stream>>>(nf, Win, xb, xTb);

  // ---- 3 hypergraph layers, 2 fused dispatches each ----
  for (int l = 0; l < 3; l++) {
    // L1: e = relu((H^T @ x) @ We) -> eT
    gemm_fused<0, 1><<<dim3(16, 1, 32), 256, 0, stream>>>(
        HTb, 2048, 2048L * 2048, 8, xTb, 2048, 128L * 2048,
        edgeWT + l * 16384,
        nullptr, 0, 0, eTb, 2048, 128L * 2048, 2048);
    // L2: x = relu((H @ e) @ Wn) -> xT (+ x on last layer for MLP)
    if (l < 2) {
      gemm_fused<0, 1><<<dim3(16, 1, 32), 256, 0, stream>>>(
          Hb, 2048, 2048L * 2048, 8, eTb, 2048, 128L * 2048,
          nodeWT + l * 16384,
          nullptr, 0, 0, xTb, 2048, 128L * 2048, 2048);
    } else {
      gemm_fused<1, 1><<<dim3(16, 1, 32), 256, 0, stream>>>(
          Hb, 2048, 2048L * 2048, 8, eTb, 2048, 128L * 2048,
          nodeWT + l * 16384,
          xb, 128, 2048L * 128, xTb, 2048, 128L * 2048, 2048);
    }
  }

  // ---- fused MLP + decode ----
  mlp_k<<<dim3(512), 256, 0, stream>>>(xb, W1T, wf, out);
}

// Round 3
// 396.781 us; speedup vs baseline: 1.4131x; 1.2204x over previous
//
#include <hip/hip_runtime.h>
#include <hip/hip_bf16.h>

// HypergraphGNN on MI355X (gfx950).
// B=4 P=8 N=E=2000 IN=16 HID=128 NL=3 MULT=4. All f32 inputs; internal bf16 MFMA.
//
// Round-3 structure:
//   convH: H -> Hb, HTb bf16 [4][2048][2048]
//   x0:    x = nf @ W_in -> xb + xTb
//   per layer (2 fused dispatches, double-buffered prefetch GEMM):
//     L1: agg = H^T@x ; e = relu(agg@We) fused ; write eT
//     L2: agg = H@e   ; x = relu(agg@Wn) fused ; write xT (+x on last layer)
//   MLP: wf = W2@Wdec ; out = 10*tanh((relu(x@W1)@wf)/sqrt(128))
//
// Heavy GEMM (gemm_fused):
//  - 128x128 tile, BK=32, 4 waves, T3-minimum 2-phase: STAGE(t+1) issued
//    BEFORE compute(t), one __syncthreads per K-step (drains vmcnt).
//  - LDS 32 KB total: double-buffered As/Bs (2x16KB); Gs (32KB) aliases the
//    staging region (only live after the main loop's final barrier).
//  - Stage-2 weight read directly from global (L2-hot, once per block).
//  - XCD-aware bijective block swizzle: XCD c owns one b, 4 p-panels.
// LDS swizzle (rule #21): linear LDS dest for global_load_lds; global source
// chunk pre-swizzled; reads apply the same involution.

typedef __attribute__((ext_vector_type(8))) short bf16x8;
typedef __attribute__((ext_vector_type(4))) float f32x4;

#define GLL16(gp, lp) __builtin_amdgcn_global_load_lds(                      \
    (const __attribute__((address_space(1))) void*)(gp),                     \
    (__attribute__((address_space(3))) void*)(lp), 16, 0, 0)

__device__ __forceinline__ unsigned short f2bf(float v) {
  __hip_bfloat16 h = __float2bfloat16(v);
  return __builtin_bit_cast(unsigned short, h);
}
__device__ __forceinline__ float bf2f(unsigned short u) {
  unsigned int x = ((unsigned int)u) << 16;
  return __builtin_bit_cast(float, x);
}

// ---------------------------------------------------------------------------
// H f32 -> Hb (straight) + HTb (transposed), bf16, padded 2000->2048 w/ zeros
__global__ void convH_k(const float* __restrict__ H,
                        unsigned short* __restrict__ Hb,
                        unsigned short* __restrict__ HTb) {
  int b  = blockIdx.z;
  int n0 = blockIdx.y * 32, e0 = blockIdx.x * 32;
  __shared__ float t[32][33];
  int tx = threadIdx.x & 31, ty = threadIdx.x >> 5;
  for (int r = ty; r < 32; r += 8) {
    int n = n0 + r, e = e0 + tx;
    float v = (n < 2000 && e < 2000) ? H[((long)b * 2000 + n) * 2000 + e] : 0.f;
    t[r][tx] = v;
    Hb[((long)b * 2048 + n) * 2048 + e] = f2bf(v);
  }
  __syncthreads();
  for (int r = ty; r < 32; r += 8) {
    HTb[((long)b * 2048 + (e0 + r)) * 2048 + (n0 + tx)] = f2bf(t[tx][r]);
  }
}

// generic f32 [R][C] -> bf16 [C][R]
__global__ void transposeW_k(const float* __restrict__ src,
                             unsigned short* __restrict__ dst, int R, int C) {
  __shared__ float t[32][33];
  int c0 = blockIdx.x * 32, r0 = blockIdx.y * 32;
  int tx = threadIdx.x & 31, ty = threadIdx.x >> 5;
  for (int rr = ty; rr < 32; rr += 8) {
    int rI = r0 + rr, cI = c0 + tx;
    t[rr][tx] = (rI < R && cI < C) ? src[(long)rI * C + cI] : 0.f;
  }
  __syncthreads();
  for (int rr = ty; rr < 32; rr += 8) {
    int cO = c0 + rr, rO = r0 + tx;
    if (cO < C && rO < R) dst[(long)cO * R + rO] = f2bf(t[tx][rr]);
  }
}

// x0 = nf @ W_in  (K=16). Writes xb [bp][2048][128] and xTb [bp][128][2048].
__global__ void x0_k(const float* __restrict__ nf, const float* __restrict__ Win,
                     unsigned short* __restrict__ xb, unsigned short* __restrict__ xTb) {
  int bp = blockIdx.y, n = blockIdx.x, d = threadIdx.x;
  float v = 0.f;
  if (n < 2000) {
    const float* row = nf + ((long)bp * 2000 + n) * 16;
#pragma unroll
    for (int k = 0; k < 16; k++) v += row[k] * Win[k * 128 + d];
  }
  unsigned short bits = f2bf(v);
  xb[((long)bp * 2048 + n) * 128 + d]  = bits;
  xTb[((long)bp * 128 + d) * 2048 + n] = bits;
}

// wf = W2 @ Wdec  (512x128 @ 128 -> 512)
__global__ void wfuse_k(const float* __restrict__ W2, const float* __restrict__ Wdec,
                        float* __restrict__ wf) {
  int i = blockIdx.x * 256 + threadIdx.x;
  if (i < 512) {
    float s = 0.f;
#pragma unroll 8
    for (int j = 0; j < 128; j++) s += W2[i * 128 + j] * Wdec[j];
    wf[i] = s;
  }
}

// ---------------------------------------------------------------------------
// Fused heavy GEMM: acc = A[2048][K=2048] @ BT[128][K]^T per (m-block, bz),
// then out = relu(acc @ W), Wt[d_out][d_in] global. Writes Cn and/or Ct.
// Grid: 512 blocks 1-D, XCD-swizzled. 256 threads.
template <int WN, int WT>
__global__ __launch_bounds__(256) void gemm_fused(
    const unsigned short* __restrict__ A, int lda, long strideA, int aDiv,
    const unsigned short* __restrict__ BT, int ldbt, long strideBT,
    const unsigned short* __restrict__ Wt,
    unsigned short* __restrict__ Cn, int ldc, long strideCn,
    unsigned short* __restrict__ Ct, int ldct, long strideCt, int K) {
  // XCD-aware bijective decode: XCD c = wgid&7 owns orig range [c*64, c*64+64)
  int wgid = blockIdx.x;
  int orig = (wgid & 7) * 64 + (wgid >> 3);
  int mblk = orig & 15;
  int bz   = orig >> 4;      // XCD c: bz in [c*4, c*4+4) -> single b per XCD
  A  += (long)(bz / aDiv) * strideA;
  BT += (long)bz * strideBT;
  int m0 = mblk * 128;

  // 32 KB LDS: staging dbuf [2][As 4096 | Bs 4096] shorts; Gs aliases all 16384
  __shared__ unsigned short smem[16384];

  int tid  = threadIdx.x;
  int lane = tid & 63;
  int w    = tid >> 6;
  int wr   = w >> 1, wc = w & 1;
  int fr   = lane & 15;   // frag row (A) / col (B,C)
  int fg   = lane >> 4;   // k-chunk (inputs) / row-subgroup (C/D)

  // staging addressing: LDS slot = tid*16B (linear); global chunk swizzled
  int sr  = tid >> 2;
  int scs = ((tid & 3) ^ ((sr >> 1) & 3)) * 8;
  const unsigned short* Ag0 = A + (long)(m0 + sr) * lda + scs;
  const unsigned short* Ag1 = A + (long)(m0 + 64 + sr) * lda + scs;
  const unsigned short* Bg0 = BT + (long)sr * ldbt + scs;
  const unsigned short* Bg1 = BT + (long)(64 + sr) * ldbt + scs;

#define STAGE(sel, kel) do {                                                 \
    unsigned short* _d = smem + (sel) * 8192 + tid * 8;                      \
    GLL16(Ag0 + (kel), _d);                                                  \
    GLL16(Ag1 + (kel), _d + 2048);                                           \
    GLL16(Bg0 + (kel), _d + 4096);                                           \
    GLL16(Bg1 + (kel), _d + 6144);                                           \
  } while (0)

  f32x4 acc[4][4] = {};
  int cIdx = (fg ^ ((fr >> 1) & 3)) * 8;  // swizzled k-chunk offset on read
  int nt = K >> 5;

  STAGE(0, 0);
  __syncthreads();  // buf0 ready
  int cur = 0;
  for (int t = 0; t < nt; ++t) {
    if (t + 1 < nt) STAGE(cur ^ 1, (t + 1) * 32);  // prefetch BEFORE compute
    const unsigned short* As_ = smem + cur * 8192;
    const unsigned short* Bs_ = As_ + 4096;
    bf16x8 af[4], bfv[4];
#pragma unroll
    for (int m = 0; m < 4; m++)
      af[m] = *(const bf16x8*)&As_[(wr * 64 + m * 16 + fr) * 32 + cIdx];
#pragma unroll
    for (int n = 0; n < 4; n++)
      bfv[n] = *(const bf16x8*)&Bs_[(wc * 64 + n * 16 + fr) * 32 + cIdx];
#pragma unroll
    for (int m = 0; m < 4; m++)
#pragma unroll
      for (int n = 0; n < 4; n++)
        acc[m][n] = __builtin_amdgcn_mfma_f32_16x16x32_bf16(af[m], bfv[n], acc[m][n], 0, 0, 0);
    __syncthreads();  // drains prefetch vmcnt; next buf ready, cur consumed
    cur ^= 1;
  }
#undef STAGE

  // acc tile -> Gs bf16 row-major (swizzled); Gs aliases dead staging buffers.
  unsigned short* Gs = smem;
#pragma unroll
  for (int m = 0; m < 4; m++) {
#pragma unroll
    for (int n = 0; n < 4; n++) {
      int rowb = wr * 64 + m * 16 + fg * 4;
      int col  = wc * 64 + n * 16 + fr;
      int ch = col >> 3, ci = col & 7;
#pragma unroll
      for (int r = 0; r < 4; r++) {
        int row = rowb + r;
        Gs[row * 128 + ((ch ^ (row & 7)) * 8) + ci] = f2bf(acc[m][n][r]);
      }
    }
  }
  __syncthreads();

  // stage 2: out = relu(G @ W). A-op = Gs; B-op = Wt rows from global (L2-hot).
  f32x4 acc2[4][4] = {};
#pragma unroll
  for (int kk = 0; kk < 4; kk++) {
    bf16x8 a2[4], b2[4];
#pragma unroll
    for (int m = 0; m < 4; m++) {
      int row = wr * 64 + m * 16 + fr;
      int c = kk * 4 + fg;
      a2[m] = *(const bf16x8*)&Gs[row * 128 + ((c ^ (row & 7)) * 8)];
    }
#pragma unroll
    for (int n = 0; n < 4; n++) {
      int row = wc * 64 + n * 16 + fr;
      b2[n] = *(const bf16x8*)&Wt[row * 128 + (kk * 4 + fg) * 8];
    }
#pragma unroll
    for (int m = 0; m < 4; m++)
#pragma unroll
      for (int n = 0; n < 4; n++)
        acc2[m][n] = __builtin_amdgcn_mfma_f32_16x16x32_bf16(a2[m], b2[n], acc2[m][n], 0, 0, 0);
  }

  // epilogue: relu + write
#pragma unroll
  for (int m = 0; m < 4; m++) {
#pragma unroll
    for (int n = 0; n < 4; n++) {
      int rowb = m0 + wr * 64 + m * 16 + fg * 4;
      int col  = wc * 64 + n * 16 + fr;
      float v0 = fmaxf(acc2[m][n][0], 0.f), v1 = fmaxf(acc2[m][n][1], 0.f);
      float v2 = fmaxf(acc2[m][n][2], 0.f), v3 = fmaxf(acc2[m][n][3], 0.f);
      if (WN) {
        unsigned short* p = Cn + bz * strideCn + (long)rowb * ldc + col;
        p[0]       = f2bf(v0);
        p[ldc]     = f2bf(v1);
        p[2 * ldc] = f2bf(v2);
        p[3 * ldc] = f2bf(v3);
      }
      if (WT) {
        ushort4 pk;
        pk.x = f2bf(v0); pk.y = f2bf(v1); pk.z = f2bf(v2); pk.w = f2bf(v3);
        *(ushort4*)(Ct + bz * strideCt + (long)col * ldct + rowb) = pk;
      }
    }
  }
}

// ---------------------------------------------------------------------------
// Fused MLP: out[row] = 10*tanh( (sum_i relu(x@W1)[row][i]*wf[i]) / sqrt(128) )
__global__ __launch_bounds__(256) void mlp_k(
    const unsigned short* __restrict__ X,    // [65536][128] bf16 (padded rows)
    const unsigned short* __restrict__ W1T,  // [512][128] bf16
    const float* __restrict__ wf,            // [512]
    float* __restrict__ out) {
  __shared__ unsigned short Xs[128 * 128];
  __shared__ unsigned short Bs[128 * 128];
  __shared__ float rowacc[128];

  int tid  = threadIdx.x;
  int lane = tid & 63;
  int w    = tid >> 6, wr = w >> 1, wc = w & 1;
  int fr   = lane & 15, fg = lane >> 4;
  long m0  = (long)blockIdx.x * 128;

#pragma unroll
  for (int i = 0; i < 8; i++) {
    int s = i * 256 + tid;
    int r = s >> 4, c = (s & 15) ^ (r & 7);
    GLL16(X + (m0 + r) * 128 + c * 8, (unsigned short*)Xs + s * 8);
  }
  if (tid < 128) rowacc[tid] = 0.f;

  float rs[4][4] = {};

  for (int nb = 0; nb < 4; nb++) {
#pragma unroll
    for (int i = 0; i < 8; i++) {
      int s = i * 256 + tid;
      int r = s >> 4, c = (s & 15) ^ (r & 7);
      GLL16(W1T + (long)(nb * 128 + r) * 128 + c * 8, (unsigned short*)Bs + s * 8);
    }
    __syncthreads();

    f32x4 acc[4][4] = {};
#pragma unroll
    for (int kk = 0; kk < 4; kk++) {
      bf16x8 a2[4], b2[4];
#pragma unroll
      for (int m = 0; m < 4; m++) {
        int row = wr * 64 + m * 16 + fr;
        int c = kk * 4 + fg;
        a2[m] = *(const bf16x8*)&Xs[row * 128 + ((c ^ (row & 7)) * 8)];
      }
#pragma unroll
      for (int n = 0; n < 4; n++) {
        int row = wc * 64 + n * 16 + fr;
        int c = kk * 4 + fg;
        b2[n] = *(const bf16x8*)&Bs[row * 128 + ((c ^ (row & 7)) * 8)];
      }
#pragma unroll
      for (int m = 0; m < 4; m++)
#pragma unroll
        for (int n = 0; n < 4; n++)
          acc[m][n] = __builtin_amdgcn_mfma_f32_16x16x32_bf16(a2[m], b2[n], acc[m][n], 0, 0, 0);
    }

#pragma unroll
    for (int n = 0; n < 4; n++) {
      float wv = wf[nb * 128 + wc * 64 + n * 16 + fr];
#pragma unroll
      for (int m = 0; m < 4; m++)
#pragma unroll
        for (int r = 0; r < 4; r++)
          rs[m][r] += fmaxf(acc[m][n][r], 0.f) * wv;
    }
    __syncthreads();
  }

#pragma unroll
  for (int m = 0; m < 4; m++)
#pragma unroll
    for (int r = 0; r < 4; r++) {
      float v = rs[m][r];
      v += __shfl_xor(v, 1, 64);
      v += __shfl_xor(v, 2, 64);
      v += __shfl_xor(v, 4, 64);
      v += __shfl_xor(v, 8, 64);
      if (fr == 0) atomicAdd(&rowacc[wr * 64 + m * 16 + fg * 4 + r], v);
    }
  __syncthreads();

  if (tid < 128) {
    long row = m0 + tid;
    int bp = (int)(row >> 11), n = (int)(row & 2047);
    if (n < 2000)
      out[(long)bp * 2000 + n] = 10.f * tanhf(rowacc[tid] * 0.08838834764831843f);
  }
}

// ---------------------------------------------------------------------------
extern "C" void kernel_launch(void* const* d_in, const int* in_sizes, int n_in,
                              void* d_out, int out_size, void* d_ws, size_t ws_size,
                              hipStream_t stream) {
  const float* nf    = (const float*)d_in[0];
  const float* H     = (const float*)d_in[1];
  const float* Win   = (const float*)d_in[2];
  const float* edgeW = (const float*)d_in[3];
  const float* nodeW = (const float*)d_in[4];
  const float* W1    = (const float*)d_in[5];
  const float* W2    = (const float*)d_in[6];
  const float* Wdec  = (const float*)d_in[7];
  float* out = (float*)d_out;

  char* ws = (char*)d_ws;
  unsigned short* Hb   = (unsigned short*)(ws + 0);          // 33.55 MB
  unsigned short* HTb  = (unsigned short*)(ws + 33554432);   // 33.55 MB
  unsigned short* xb   = (unsigned short*)(ws + 67108864);   // 16.78 MB
  unsigned short* xTb  = (unsigned short*)(ws + 83886080);   // 16.78 MB
  unsigned short* eTb  = (unsigned short*)(ws + 100663296);  // 16.78 MB
  unsigned short* edgeWT = (unsigned short*)(ws + 117440512);
  unsigned short* nodeWT = (unsigned short*)(ws + 117538816);
  unsigned short* W1T    = (unsigned short*)(ws + 117637120);
  float*          wf     = (float*)(ws + 117768192);
  (void)ws_size; (void)in_sizes; (void)n_in; (void)out_size;

  // ---- input prep ----
  convH_k<<<dim3(64, 64, 4), 256, 0, stream>>>(H, Hb, HTb);
  for (int l = 0; l < 3; l++) {
    transposeW_k<<<dim3(4, 4), 256, 0, stream>>>(edgeW + l * 16384, edgeWT + l * 16384, 128, 128);
    transposeW_k<<<dim3(4, 4), 256, 0, stream>>>(nodeW + l * 16384, nodeWT + l * 16384, 128, 128);
  }
  transposeW_k<<<dim3(16, 4), 256, 0, stream>>>(W1, W1T, 128, 512);
  wfuse_k<<<2, 256, 0, stream>>>(W2, Wdec, wf);
  x0_k<<<dim3(2048, 32), 128, 0, stream>>>(nf, Win, xb, xTb);

  // ---- 3 hypergraph layers, 2 fused dispatches each ----
  for (int l = 0; l < 3; l++) {
    // L1: e = relu((H^T @ x) @ We) -> eT
    gemm_fused<0, 1><<<dim3(512), 256, 0, stream>>>(
        HTb, 2048, 2048L * 2048, 8, xTb, 2048, 128L * 2048,
        edgeWT + l * 16384,
        nullptr, 0, 0, eTb, 2048, 128L * 2048, 2048);
    // L2: x = relu((H @ e) @ Wn) -> xT (+ x on last layer for MLP)
    if (l < 2) {
      gemm_fused<0, 1><<<dim3(512), 256, 0, stream>>>(
          Hb, 2048, 2048L * 2048, 8, eTb, 2048, 128L * 2048,
          nodeWT + l * 16384,
          nullptr, 0, 0, xTb, 2048, 128L * 2048, 2048);
    } else {
      gemm_fused<1, 1><<<dim3(512), 256, 0, stream>>>(
          Hb, 2048, 2048L * 2048, 8, eTb, 2048, 128L * 2048,
          nodeWT + l * 16384,
          xb, 128, 2048L * 128, xTb, 2048, 128L * 2048, 2048);
    }
  }

  // ---- fused MLP + decode ----
  mlp_k<<<dim3(512), 256, 0, stream>>>(xb, W1T, wf, out);
}